// Round 4
// baseline (101.529 us; speedup 1.0000x reference)
//
#include <hip/hip_runtime.h>
#include <hip/hip_fp16.h>

// INT4 asymmetric weight decompressor.
// d_in[0] x:        33,554,432 int32, each holding 2 uint4 nibbles (low first)
// d_in[1] scale:    524,288 float32 (fp16 values upcast by the harness)
// d_in[2] zp_packed: 262,144 int32, each holding 2 uint4 zero points (low first)
// d_out   out:      67,108,864 fp32 = (w - zp) * scale, rounded through fp16
//
// Each thread-iteration: one int4 load (4 packed words = 8 outputs, 16 B/lane)
// -> two nontemporal float4 stores (32 B/lane).
//   8 outputs start at flat index 8i; group gl = 8i/128 = i>>4 (uniform across
//   the 8 outputs since 8 | 128).  zp word = zp[gl>>1], nibble (gl&1).

typedef float f32x4 __attribute__((ext_vector_type(4)));   // clang vector: OK for nontemporal builtin

__global__ void __launch_bounds__(256)
int4_dequant_kernel(const int* __restrict__ x,
                    const float* __restrict__ scale,
                    const int* __restrict__ zp,
                    float* __restrict__ out,
                    int niter)
{
    const int stride = gridDim.x * blockDim.x;
    for (int i = blockIdx.x * blockDim.x + threadIdx.x; i < niter; i += stride) {
        int4 w = reinterpret_cast<const int4*>(x)[i];

        int gl   = i >> 4;                 // group linear index (out_ch*64 + g)
        float s  = scale[gl];              // fp32, exactly fp16-representable
        int zpw  = zp[gl >> 1];
        float zf = (float)((zpw >> ((gl & 1) << 2)) & 15);

        // fp32 product of an fp16-representable scale and a <=5-bit int is
        // exact; one rounding to fp16 reproduces the reference's fp16 multiply.
        f32x4 o0, o1;
        o0.x = (float)(_Float16)(((float)( w.x       & 15) - zf) * s);
        o0.y = (float)(_Float16)(((float)((w.x >> 4) & 15) - zf) * s);
        o0.z = (float)(_Float16)(((float)( w.y       & 15) - zf) * s);
        o0.w = (float)(_Float16)(((float)((w.y >> 4) & 15) - zf) * s);
        o1.x = (float)(_Float16)(((float)( w.z       & 15) - zf) * s);
        o1.y = (float)(_Float16)(((float)((w.z >> 4) & 15) - zf) * s);
        o1.z = (float)(_Float16)(((float)( w.w       & 15) - zf) * s);
        o1.w = (float)(_Float16)(((float)((w.w >> 4) & 15) - zf) * s);

        f32x4* dst = reinterpret_cast<f32x4*>(out) + 2 * (size_t)i;
        __builtin_nontemporal_store(o0, dst);
        __builtin_nontemporal_store(o1, dst + 1);
    }
}

extern "C" void kernel_launch(void* const* d_in, const int* in_sizes, int n_in,
                              void* d_out, int out_size, void* d_ws, size_t ws_size,
                              hipStream_t stream) {
    const int*   x     = (const int*)d_in[0];
    const float* scale = (const float*)d_in[1];
    const int*   zp    = (const int*)d_in[2];
    float*       out   = (float*)d_out;

    const int niter = out_size / 8;   // 8 outputs per iteration = 8,388,608

    dim3 grid(2048), block(256);      // 8 blocks/CU, 32 waves/CU, grid-stride x16
    hipLaunchKernelGGL(int4_dequant_kernel, grid, block, 0, stream,
                       x, scale, zp, out, niter);
}

// Round 5
// 95.086 us; speedup vs baseline: 1.0678x; 1.0678x over previous
//
#include <hip/hip_runtime.h>
#include <hip/hip_fp16.h>

// INT4 asymmetric weight decompressor.
// d_in[0] x:        33,554,432 int32, each holding 2 uint4 nibbles (low first)
// d_in[1] scale:    524,288 float32 (fp16 values upcast by the harness)
// d_in[2] zp_packed: 262,144 int32, each holding 2 uint4 zero points (low first)
// d_out   out:      67,108,864 fp32 = (w - zp) * scale, rounded through fp16
//
// Each thread-iteration: one int4 load (4 packed words = 8 outputs, 16 B/lane)
// -> two float4 stores (32 B/lane, cached: L3 write-absorption helps, R4 showed
//    nontemporal stores regress 84->101 us).
//   8 outputs start at flat index 8i; group gl = 8i/128 = i>>4 (uniform across
//   the 8 outputs since 8 | 128).  zp word = zp[gl>>1], nibble (gl&1).

__global__ void __launch_bounds__(256)
int4_dequant_kernel(const int* __restrict__ x,
                    const float* __restrict__ scale,
                    const int* __restrict__ zp,
                    float* __restrict__ out,
                    int niter)
{
    const int stride = gridDim.x * blockDim.x;
    for (int i = blockIdx.x * blockDim.x + threadIdx.x; i < niter; i += stride) {
        int4 w = reinterpret_cast<const int4*>(x)[i];

        int gl   = i >> 4;                 // group linear index (out_ch*64 + g)
        float s  = scale[gl];              // fp32, exactly fp16-representable
        int zpw  = zp[gl >> 1];
        float zf = (float)((zpw >> ((gl & 1) << 2)) & 15);

        // fp32 product of an fp16-representable scale and a <=5-bit int is
        // exact; one rounding to fp16 reproduces the reference's fp16 multiply.
        float4 o0, o1;
        o0.x = (float)(_Float16)(((float)( w.x       & 15) - zf) * s);
        o0.y = (float)(_Float16)(((float)((w.x >> 4) & 15) - zf) * s);
        o0.z = (float)(_Float16)(((float)( w.y       & 15) - zf) * s);
        o0.w = (float)(_Float16)(((float)((w.y >> 4) & 15) - zf) * s);
        o1.x = (float)(_Float16)(((float)( w.z       & 15) - zf) * s);
        o1.y = (float)(_Float16)(((float)((w.z >> 4) & 15) - zf) * s);
        o1.z = (float)(_Float16)(((float)( w.w       & 15) - zf) * s);
        o1.w = (float)(_Float16)(((float)((w.w >> 4) & 15) - zf) * s);

        float4* dst = reinterpret_cast<float4*>(out) + 2 * (size_t)i;
        dst[0] = o0;
        dst[1] = o1;
    }
}

extern "C" void kernel_launch(void* const* d_in, const int* in_sizes, int n_in,
                              void* d_out, int out_size, void* d_ws, size_t ws_size,
                              hipStream_t stream) {
    const int*   x     = (const int*)d_in[0];
    const float* scale = (const float*)d_in[1];
    const int*   zp    = (const int*)d_in[2];
    float*       out   = (float*)d_out;

    const int niter = out_size / 8;   // 8 outputs per iteration = 8,388,608

    dim3 grid(2048), block(256);      // 8 blocks/CU, 32 waves/CU, grid-stride x16
    hipLaunchKernelGGL(int4_dequant_kernel, grid, block, 0, stream,
                       x, scale, zp, out, niter);
}

// Round 6
// 90.736 us; speedup vs baseline: 1.1190x; 1.0479x over previous
//
#include <hip/hip_runtime.h>
#include <hip/hip_fp16.h>

// INT4 asymmetric weight decompressor.
// d_in[0] x:        33,554,432 int32, each holding 2 uint4 nibbles (low first)
// d_in[1] scale:    524,288 float32 (fp16 values upcast by the harness)
// d_in[2] zp_packed: 262,144 int32, each holding 2 uint4 zero points (low first)
// d_out   out:      67,108,864 fp32 = (w - zp) * scale, rounded through fp16
//
// R2 shape (best, 84us): per chunk one int2 load (8B/lane dense) -> one float4
// store (16B/lane dense). R5 lesson: wider per-thread access makes individual
// stores lane-strided (half-line bursts) -> +13%. So keep 4-output chunks but
// unroll the grid-stride loop x4 with BATCHED independent loads for MLP.
//   chunk c: gl = c>>5 (128 outs/group), zp word = zp[gl>>1], nibble (gl&1).

__global__ void __launch_bounds__(256)
int4_dequant_kernel(const int* __restrict__ x,
                    const float* __restrict__ scale,
                    const int* __restrict__ zp,
                    float* __restrict__ out,
                    int niter)
{
    const int S   = gridDim.x * blockDim.x;          // 524,288 threads
    const int tid = blockIdx.x * blockDim.x + threadIdx.x;
    const int2*  x2  = reinterpret_cast<const int2*>(x);
    float4*      o4  = reinterpret_cast<float4*>(out);

    int j = tid;
    // main unrolled loop: 4 independent chunks in flight (niter = 32*S exactly,
    // so the tail loop below never runs for the bench shape; kept for safety)
    for (; j + 3 * (long long)S < niter; j += 4 * S) {
        int c0 = j, c1 = j + S, c2 = j + 2 * S, c3 = j + 3 * S;

        // batch all loads first — 4 independent int2 + scale/zp (L2-resident)
        int2 w0 = x2[c0];
        int2 w1 = x2[c1];
        int2 w2 = x2[c2];
        int2 w3 = x2[c3];

        int g0 = c0 >> 5, g1 = c1 >> 5, g2 = c2 >> 5, g3 = c3 >> 5;
        float s0 = scale[g0], s1 = scale[g1], s2 = scale[g2], s3 = scale[g3];
        int zw0 = zp[g0 >> 1], zw1 = zp[g1 >> 1], zw2 = zp[g2 >> 1], zw3 = zp[g3 >> 1];

        float z0 = (float)((zw0 >> ((g0 & 1) << 2)) & 15);
        float z1 = (float)((zw1 >> ((g1 & 1) << 2)) & 15);
        float z2 = (float)((zw2 >> ((g2 & 1) << 2)) & 15);
        float z3 = (float)((zw3 >> ((g3 & 1) << 2)) & 15);

        // fp32 product of an fp16-representable scale and a <=5-bit int is
        // exact; one rounding to fp16 reproduces the reference's fp16 multiply.
        float4 o;
        o.x = (float)(_Float16)(((float)( w0.x       & 15) - z0) * s0);
        o.y = (float)(_Float16)(((float)((w0.x >> 4) & 15) - z0) * s0);
        o.z = (float)(_Float16)(((float)( w0.y       & 15) - z0) * s0);
        o.w = (float)(_Float16)(((float)((w0.y >> 4) & 15) - z0) * s0);
        o4[c0] = o;
        o.x = (float)(_Float16)(((float)( w1.x       & 15) - z1) * s1);
        o.y = (float)(_Float16)(((float)((w1.x >> 4) & 15) - z1) * s1);
        o.z = (float)(_Float16)(((float)( w1.y       & 15) - z1) * s1);
        o.w = (float)(_Float16)(((float)((w1.y >> 4) & 15) - z1) * s1);
        o4[c1] = o;
        o.x = (float)(_Float16)(((float)( w2.x       & 15) - z2) * s2);
        o.y = (float)(_Float16)(((float)((w2.x >> 4) & 15) - z2) * s2);
        o.z = (float)(_Float16)(((float)( w2.y       & 15) - z2) * s2);
        o.w = (float)(_Float16)(((float)((w2.y >> 4) & 15) - z2) * s2);
        o4[c2] = o;
        o.x = (float)(_Float16)(((float)( w3.x       & 15) - z3) * s3);
        o.y = (float)(_Float16)(((float)((w3.x >> 4) & 15) - z3) * s3);
        o.z = (float)(_Float16)(((float)( w3.y       & 15) - z3) * s3);
        o.w = (float)(_Float16)(((float)((w3.y >> 4) & 15) - z3) * s3);
        o4[c3] = o;
    }
    // generic tail (never runs for the bench shape)
    for (; j < niter; j += S) {
        int2 w = x2[j];
        int gl = j >> 5;
        float s  = scale[gl];
        int zpw  = zp[gl >> 1];
        float zf = (float)((zpw >> ((gl & 1) << 2)) & 15);
        float4 o;
        o.x = (float)(_Float16)(((float)( w.x       & 15) - zf) * s);
        o.y = (float)(_Float16)(((float)((w.x >> 4) & 15) - zf) * s);
        o.z = (float)(_Float16)(((float)( w.y       & 15) - zf) * s);
        o.w = (float)(_Float16)(((float)((w.y >> 4) & 15) - zf) * s);
        o4[j] = o;
    }
}

extern "C" void kernel_launch(void* const* d_in, const int* in_sizes, int n_in,
                              void* d_out, int out_size, void* d_ws, size_t ws_size,
                              hipStream_t stream) {
    const int*   x     = (const int*)d_in[0];
    const float* scale = (const float*)d_in[1];
    const int*   zp    = (const int*)d_in[2];
    float*       out   = (float*)d_out;

    const int niter = out_size / 4;   // 4 outputs per chunk = 16,777,216 chunks

    dim3 grid(2048), block(256);      // 524,288 threads -> exactly 32 chunks each
    hipLaunchKernelGGL(int4_dequant_kernel, grid, block, 0, stream,
                       x, scale, zp, out, niter);
}

// Round 7
// 76.532 us; speedup vs baseline: 1.3266x; 1.1856x over previous
//
#include <hip/hip_runtime.h>
#include <hip/hip_fp16.h>

// INT4 asymmetric weight decompressor.
// d_in[0] x:        33,554,432 int32, each holding 2 uint4 nibbles (low first)
// d_in[1] scale:    524,288 float32 (fp16 values upcast by the harness)
// d_in[2] zp_packed: 262,144 int32, each holding 2 uint4 zero points (low first)
// d_out   out:      67,108,864 fp32 = (w - zp) * scale, rounded through fp16
//
// Structure = R2 (best, 84us): grid-stride, per iter one dense int2 load
// (8B/lane) -> one dense float4 store (16B/lane). Lessons: nt stores -21%
// (R4, lose L3 write absorption); 16B/lane loads -13% (R5, stores go
// half-line); 4x strided batching -8% (R6, DRAM stream explosion; latency
// was never the limit: even serialized waves demand >>HBM BW).
// Single change vs R2: NONTEMPORAL loads on the read-once x stream so it
// doesn't thrash L2/L3 against the 268 MB write stream. scale/zp stay
// cached (cross-wave reuse).

typedef int i32x2 __attribute__((ext_vector_type(2)));  // clang vector: OK for nontemporal builtin

__global__ void __launch_bounds__(256)
int4_dequant_kernel(const int* __restrict__ x,
                    const float* __restrict__ scale,
                    const int* __restrict__ zp,
                    float* __restrict__ out,
                    int niter)
{
    const int stride = gridDim.x * blockDim.x;
    const i32x2* x2 = reinterpret_cast<const i32x2*>(x);
    for (int i = blockIdx.x * blockDim.x + threadIdx.x; i < niter; i += stride) {
        i32x2 w = __builtin_nontemporal_load(x2 + i);

        int gl   = i >> 5;                 // group linear index (out_ch*64 + g)
        float s  = scale[gl];              // fp32, exactly fp16-representable
        int zpw  = zp[gl >> 1];
        float zf = (float)((zpw >> ((gl & 1) << 2)) & 15);

        // fp32 product of an fp16-representable scale and a <=5-bit int is
        // exact; one rounding to fp16 reproduces the reference's fp16 multiply.
        float4 o;
        o.x = (float)(_Float16)(((float)( w.x       & 15) - zf) * s);
        o.y = (float)(_Float16)(((float)((w.x >> 4) & 15) - zf) * s);
        o.z = (float)(_Float16)(((float)( w.y       & 15) - zf) * s);
        o.w = (float)(_Float16)(((float)((w.y >> 4) & 15) - zf) * s);

        reinterpret_cast<float4*>(out)[i] = o;
    }
}

extern "C" void kernel_launch(void* const* d_in, const int* in_sizes, int n_in,
                              void* d_out, int out_size, void* d_ws, size_t ws_size,
                              hipStream_t stream) {
    const int*   x     = (const int*)d_in[0];
    const float* scale = (const float*)d_in[1];
    const int*   zp    = (const int*)d_in[2];
    float*       out   = (float*)d_out;

    const int niter = out_size / 4;   // 4 outputs per iteration = 16,777,216

    dim3 grid(2048), block(256);      // 8 blocks/CU, 32 waves/CU, grid-stride x32
    hipLaunchKernelGGL(int4_dequant_kernel, grid, block, 0, stream,
                       x, scale, zp, out, niter);
}

// Round 8
// 69.973 us; speedup vs baseline: 1.4510x; 1.0937x over previous
//
#include <hip/hip_runtime.h>
#include <hip/hip_fp16.h>

// INT4 asymmetric weight decompressor.
// d_in[0] x:        33,554,432 int32, each holding 2 uint4 nibbles (low first)
// d_in[1] scale:    524,288 float32 (fp16 values upcast by the harness)
// d_in[2] zp_packed: 262,144 int32, each holding 2 uint4 zero points (low first)
// d_out   out:      67,108,864 fp32 = (w - zp) * scale, rounded through fp16
//
// Structure = R7 winner (76.5us): grid-stride, per iter one dense nontemporal
// int2 load (8B/lane) -> one dense cached float4 store (16B/lane).
// Ledger: nt stores -21% (R4); 16B/lane loads -13% (R5); batch-4 -8% (R6);
// nt loads +9% (R7, stops read stream evicting L3 write-absorption lines).
// Single change vs R7: side loads (scale, zp) moved to the SCALAR path.
//   zp word index zi = i>>6 is wave-uniform (S % 64 == 0); the wave's two
//   scale values are one aligned float2 at scale[2*zi]. readfirstlane makes
//   the index provably uniform -> s_load, removing 1/3 of vector VMEM ops
//   and all side-load L1/TA traffic. Lane half selects scale component and
//   zp nibble: lanes 0-31 -> (sc.x, low nibble), lanes 32-63 -> (sc.y, high).

typedef int i32x2 __attribute__((ext_vector_type(2)));

__global__ void __launch_bounds__(256)
int4_dequant_kernel(const int* __restrict__ x,
                    const float* __restrict__ scale,
                    const int* __restrict__ zp,
                    float* __restrict__ out,
                    int niter)
{
    const int S    = gridDim.x * blockDim.x;          // 524,288 (mult of 64)
    const int tid  = blockIdx.x * blockDim.x + threadIdx.x;
    const int hi   = (threadIdx.x >> 5) & 1;          // 0: lanes 0-31, 1: lanes 32-63
    const int zstep = S >> 6;                          // 8,192 (uniform)
    // wave-uniform starting zp-word index, forced into SGPR
    int zi = __builtin_amdgcn_readfirstlane(tid >> 6);

    const i32x2*  x2  = reinterpret_cast<const i32x2*>(x);
    const float2* sc2 = reinterpret_cast<const float2*>(scale);

    for (int i = tid; i < niter; i += S, zi += zstep) {
        i32x2 w = __builtin_nontemporal_load(x2 + i);

        int    zpw = zp[zi];          // uniform addr -> s_load_dword
        float2 sc  = sc2[zi];         // uniform addr -> s_load_dwordx2

        float s  = hi ? sc.y : sc.x;
        float zf = (float)((zpw >> (hi << 2)) & 15);

        // fp32 product of an fp16-representable scale and a <=5-bit int is
        // exact; one rounding to fp16 reproduces the reference's fp16 multiply.
        float4 o;
        o.x = (float)(_Float16)(((float)( w.x       & 15) - zf) * s);
        o.y = (float)(_Float16)(((float)((w.x >> 4) & 15) - zf) * s);
        o.z = (float)(_Float16)(((float)( w.y       & 15) - zf) * s);
        o.w = (float)(_Float16)(((float)((w.y >> 4) & 15) - zf) * s);

        reinterpret_cast<float4*>(out)[i] = o;
    }
}

extern "C" void kernel_launch(void* const* d_in, const int* in_sizes, int n_in,
                              void* d_out, int out_size, void* d_ws, size_t ws_size,
                              hipStream_t stream) {
    const int*   x     = (const int*)d_in[0];
    const float* scale = (const float*)d_in[1];
    const int*   zp    = (const int*)d_in[2];
    float*       out   = (float*)d_out;

    const int niter = out_size / 4;   // 4 outputs per iteration = 16,777,216

    dim3 grid(2048), block(256);      // 8 blocks/CU, 32 waves/CU, grid-stride x32
    hipLaunchKernelGGL(int4_dequant_kernel, grid, block, 0, stream,
                       x, scale, zp, out, niter);
}